// Round 4
// baseline (164.230 us; speedup 1.0000x reference)
//
#include <hip/hip_runtime.h>

#define N 1681
#define BS 32
#define BAND 41
#define NBLOCKS (BS * BAND)       // 1312
#define THREADS 256
#define NROWS_TOTAL (BS * N)      // 53792
#define MAXC ((BS * N * N) / 4)   // 22605848 float4 chunks in each input

// ws layout: dpart[NBLOCKS*N] f32 | sp[53792] f32 | st[53792] f32 | bsums[128] f64

__global__ __launch_bounds__(THREADS, 2) void pass1_kernel(
    const float* __restrict__ pred,
    const float* __restrict__ targ,
    float* __restrict__ sp,
    float* __restrict__ st,
    float* __restrict__ dpart) {
  __shared__ float dsum[N];

  const int b    = blockIdx.x;      // 0..1311
  const int tid  = threadIdx.x;
  const int lane = tid & 63;
  const int wid  = tid >> 6;        // 0..3; also the row alignment class h
  const long R0  = (long)b * BAND;  // first global row of this block

  for (int idx = tid; idx < N; idx += THREADS) dsum[idx] = 0.0f;
  __syncthreads();

  const float4* __restrict__ pred4 = (const float4*)pred;
  const float4* __restrict__ targ4 = (const float4*)targ;

  const int h = wid;                // rows assigned so that (R & 3) == wid
  float dprod[7][4];
#pragma unroll
  for (int t2 = 0; t2 < 7; ++t2)
#pragma unroll
    for (int ee = 0; ee < 4; ++ee) dprod[t2][ee] = 0.0f;

  float4 pA[7], tA[7], pB[7], tB[7];

  // branchless, clamped loads: all 14 float4 loads issue unconditionally;
  // out-of-row lanes are discarded by the compute-side column mask.
#define LOADROW(PBUF, TBUF, CBASE) do {                                  \
    _Pragma("unroll")                                                    \
    for (int t2 = 0; t2 < 7; ++t2) {                                     \
      const int c_ = min((CBASE) + t2 * 64 + lane, MAXC - 1);            \
      PBUF[t2] = pred4[c_];                                              \
      TBUF[t2] = targ4[c_];                                              \
    }                                                                    \
  } while (0)

#define COMPROW(PBUF, TBUF, RR) do {                                     \
    const long R_ = R0 + (RR);                                           \
    float psq = 0.0f, tsq = 0.0f;                                        \
    _Pragma("unroll")                                                    \
    for (int t2 = 0; t2 < 7; ++t2) {                                     \
      const float pv[4] = {PBUF[t2].x, PBUF[t2].y, PBUF[t2].z, PBUF[t2].w}; \
      const float tv[4] = {TBUF[t2].x, TBUF[t2].y, TBUF[t2].z, TBUF[t2].w}; \
      if (t2 == 0 || t2 == 6) {                                          \
        const int colb = t2 * 256 + 4 * lane - h;                        \
        _Pragma("unroll")                                                \
        for (int ee = 0; ee < 4; ++ee) {                                 \
          const bool ok = (unsigned)(colb + ee) < (unsigned)N;           \
          const float pm = ok ? pv[ee] : 0.0f;                           \
          const float tm = ok ? tv[ee] : 0.0f;                           \
          psq = fmaf(pm, pm, psq);                                       \
          tsq = fmaf(tm, tm, tsq);                                       \
          dprod[t2][ee] = fmaf(pm, tm, dprod[t2][ee]);                   \
        }                                                                \
      } else {                                                           \
        _Pragma("unroll")                                                \
        for (int ee = 0; ee < 4; ++ee) {                                 \
          psq = fmaf(pv[ee], pv[ee], psq);                               \
          tsq = fmaf(tv[ee], tv[ee], tsq);                               \
          dprod[t2][ee] = fmaf(pv[ee], tv[ee], dprod[t2][ee]);           \
        }                                                                \
      }                                                                  \
    }                                                                    \
    _Pragma("unroll")                                                    \
    for (int off = 32; off > 0; off >>= 1) {                             \
      psq += __shfl_down(psq, off, 64);                                  \
      tsq += __shfl_down(tsq, off, 64);                                  \
    }                                                                    \
    if (lane == 0) { sp[R_] = psq; st[R_] = tsq; }                       \
  } while (0)

  // first rr with (R0 + rr) & 3 == wid; its first chunk index (int: < 2^25)
  const int rr0 = (wid - (int)(R0 & 3)) & 3;
  const int c0  = (int)(((R0 + rr0) * (long)N) >> 2);

  // 2-deep ping-pong pipeline; 4 rows ahead = +N chunks (4*N elems / 4)
  int rr = rr0;
  int cA = c0;
  LOADROW(pA, tA, cA);
  for (;;) {
    const int r1 = rr + 4;
    if (r1 < BAND) LOADROW(pB, tB, cA + N);
    COMPROW(pA, tA, rr);
    if (r1 >= BAND) break;
    const int r2 = r1 + 4;
    if (r2 < BAND) LOADROW(pA, tA, cA + 2 * N);
    COMPROW(pB, tB, r1);
    if (r2 >= BAND) break;
    rr = r2;
    cA += 2 * N;
  }

  // fold per-wave register accumulators into LDS (column j of this band)
#pragma unroll
  for (int t2 = 0; t2 < 7; ++t2)
#pragma unroll
    for (int ee = 0; ee < 4; ++ee) {
      const int col = t2 * 256 + 4 * lane + ee - h;
      if ((unsigned)col < (unsigned)N) atomicAdd(&dsum[col], dprod[t2][ee]);
    }
  __syncthreads();

  // plain coalesced store of this block's column-dot partial (no pre-zero, no atomics)
  for (int idx = tid; idx < N; idx += THREADS)
    dpart[(size_t)b * N + idx] = dsum[idx];
}

__global__ __launch_bounds__(THREADS) void fin1_kernel(
    const float* __restrict__ sp,
    const float* __restrict__ st,
    const float* __restrict__ dpart,
    double* __restrict__ bsums) {
  __shared__ double red[4];

  double acc = 0.0;
  for (int g = blockIdx.x * THREADS + threadIdx.x; g < NROWS_TOTAL;
       g += gridDim.x * THREADS) {
    const int l = g / N;          // matrix
    const int j = g - l * N;      // column
    float dv = 0.0f;
    const float* __restrict__ dp = dpart + (size_t)l * BAND * N + j;
#pragma unroll 41
    for (int band = 0; band < BAND; ++band) dv += dp[(size_t)band * N];
    const double s = (double)sp[g] * (double)st[g];
    acc += (double)dv / sqrt(s);
  }
#pragma unroll
  for (int off = 32; off > 0; off >>= 1) acc += __shfl_down(acc, off, 64);
  const int wid = threadIdx.x >> 6;
  if ((threadIdx.x & 63) == 0) red[wid] = acc;
  __syncthreads();
  if (threadIdx.x == 0)
    bsums[blockIdx.x] = red[0] + red[1] + red[2] + red[3];
}

__global__ __launch_bounds__(64) void fin2_kernel(
    const double* __restrict__ bsums, float* __restrict__ out) {
  double acc = bsums[threadIdx.x] + bsums[threadIdx.x + 64];
#pragma unroll
  for (int off = 32; off > 0; off >>= 1) acc += __shfl_down(acc, off, 64);
  if (threadIdx.x == 0)
    out[0] = (float)(-acc / ((double)BS * (double)N));
}

extern "C" void kernel_launch(void* const* d_in, const int* in_sizes, int n_in,
                              void* d_out, int out_size, void* d_ws, size_t ws_size,
                              hipStream_t stream) {
  const float* pred = (const float*)d_in[0];
  const float* targ = (const float*)d_in[1];

  float* ws     = (float*)d_ws;
  float* dpart  = ws;                                   // NBLOCKS*N floats (~8.8 MB)
  float* sp     = ws + (size_t)NBLOCKS * N;             // 53792 floats
  float* st     = sp + (size_t)NROWS_TOTAL;             // 53792 floats
  double* bsums = (double*)(st + (size_t)NROWS_TOTAL + 32);  // 128 doubles (8B-aligned pad)

  pass1_kernel<<<NBLOCKS, THREADS, 0, stream>>>(pred, targ, sp, st, dpart);
  fin1_kernel<<<128, THREADS, 0, stream>>>(sp, st, dpart, bsums);
  fin2_kernel<<<1, 64, 0, stream>>>(bsums, (float*)d_out);
}